// Round 2
// baseline (354.883 us; speedup 1.0000x reference)
//
#include <hip/hip_runtime.h>
#include <math.h>

#define N_NODES   50000
#define F_IN      2048
#define E_ADJ     800000
#define NNZ_FEAT  1600000
#define HID       64
#define NCLS      40
#define FEAT_PASSES 4
#define ADJ_PASSES  2

// Fixed-capacity per-row slabs (degrees Poisson(32)/Poisson(16), max ~58/~35).
#define SLAB_F    80    // 640 B / row (multiple of 8)
#define SLAB_A    48    // 384 B / row (multiple of 8)

// One fill counter per 64B cache line.
#define FILL_STRIDE 16

typedef unsigned short ushort_t;
typedef unsigned int   uint_t;
typedef _Float16 half8v __attribute__((ext_vector_type(8)));
typedef float    float4v __attribute__((ext_vector_type(4)));

// ---------------------------------------------------------------------------
// Slab scatter. e.x holds the PRE-SCALED byte offset (col*stride) so the SpMM
// gather address is a single 32-bit add; e.y holds the fp32 value bits.
// ---------------------------------------------------------------------------
__global__ void slab_scatter_kernel(const int* __restrict__ rows, const int* __restrict__ cols,
                                    const float* __restrict__ vals, int nnz,
                                    int rlo, int rhi, int slab_cap, int col_scale,
                                    int* __restrict__ fill, int2* __restrict__ slab) {
    int i = blockIdx.x * blockDim.x + threadIdx.x;
    if (i < nnz) {
        int r = rows[i];
        if (r >= rlo && r < rhi) {
            int p = atomicAdd(&fill[(size_t)r * FILL_STRIDE], 1);
            if (p < slab_cap) {
                int2 e;
                e.x = cols[i] * col_scale;
                e.y = __float_as_int(vals[i]);
                slab[(size_t)r * slab_cap + p] = e;
            }
        }
    }
}

// ---------------------------------------------------------------------------
// Zero-pad each slab row from its fill count up to roundup8(own fill).
// Padded entries are {byteoff 0, value 0.0f} -> fma no-ops. Gather kernels
// then loop each row to its own 8-multiple bound with no tails/branches.
// ---------------------------------------------------------------------------
__global__ void slab_pad_kernel(const int* __restrict__ featFill, int2* __restrict__ featSlab,
                                const int* __restrict__ adjFill,  int2* __restrict__ adjSlab) {
    int i = blockIdx.x * blockDim.x + threadIdx.x;
    const int perSlab = N_NODES * 8;
    const int* fill; int2* slab; int cap; int idx;
    if (i < perSlab)              { fill = featFill; slab = featSlab; cap = SLAB_F; idx = i; }
    else if (i < 2 * perSlab)     { fill = adjFill;  slab = adjSlab;  cap = SLAB_A; idx = i - perSlab; }
    else return;
    int r  = idx >> 3;
    int k  = idx & 7;
    int s  = min(fill[(size_t)r * FILL_STRIDE], cap);
    int tgt = (s + 7) & ~7;            // <= cap since cap % 8 == 0
    int2 z; z.x = 0; z.y = 0;
    for (int slot = s + k; slot < tgt; slot += 8)
        slab[(size_t)r * cap + slot] = z;
}

// Pack w1|w2|w3 -> fp16 wcat[2048][192].
__global__ void wcat_kernel(const float* __restrict__ w1, const float* __restrict__ w2,
                            const float* __restrict__ w3, _Float16* __restrict__ wcat) {
    int i = blockIdx.x * blockDim.x + threadIdx.x;     // over 2048*64
    if (i < F_IN * HID) {
        int f = i >> 6, c = i & 63;
        wcat[(size_t)f * 192 + c]       = (_Float16)w1[i];
        wcat[(size_t)f * 192 + 64 + c]  = (_Float16)w2[i];
        wcat[(size_t)f * 192 + 128 + c] = (_Float16)w3[i];
    }
}

// fc_w [192x40] -> class-major fp16 fcwB[48][192] (cols 40..47 zero).
__global__ void fcwb_kernel(const float* __restrict__ fc_w, _Float16* __restrict__ fcwB) {
    int i = blockIdx.x * blockDim.x + threadIdx.x;     // over 48*192
    if (i < 48 * 192) {
        int c = i / 192, k = i - c * 192;
        fcwB[i] = (c < NCLS) ? (_Float16)fc_w[k * NCLS + c] : (_Float16)0.0f;
    }
}

// ---------------------------------------------------------------------------
// SpMM feat @ wcat + bias, relu. ONE WAVE PER ROW (4 rows / 256-thread block).
// Lane l (<48) owns cols 4l..4l+3; one dwordx2 (8B) gather per slab entry per
// wave (was 3 x 2B wave-instrs per entry). Row index forced scalar via
// readfirstlane so slab loads stay s_load (off the VMEM pipe).
// Branch0 -> hb[:,0:64]; br 1,2 -> xb[N,128].
// ---------------------------------------------------------------------------
__global__ void spmm_feat_kernel(const int* __restrict__ fill, const int2* __restrict__ slab,
                                 const _Float16* __restrict__ wcat,
                                 const float* __restrict__ b1, const float* __restrict__ b2,
                                 const float* __restrict__ b3,
                                 _Float16* __restrict__ hb, _Float16* __restrict__ xb) {
    int lane = threadIdx.x & 63;
    int r = __builtin_amdgcn_readfirstlane((int)(blockIdx.x * 4 + (threadIdx.x >> 6)));
    const int2* ecv = slab + (size_t)r * SLAB_F;
    int e = (min(fill[(size_t)r * FILL_STRIDE], SLAB_F) + 7) & ~7;

    if (lane < 48) {
        int c0 = 4 * lane;                    // 0..188
        const float* bsel = (c0 < 64) ? b1 : (c0 < 128) ? b2 : b3;
        int cb = c0 & 63;
        float a0 = bsel[cb], a1 = bsel[cb + 1], a2 = bsel[cb + 2], a3 = bsel[cb + 3];
        uint_t l8 = 8u * (uint_t)lane;
        const char* wb = (const char*)wcat;

        for (int j = 0; j < e; j += 8) {
            int4 p0 = *(const int4*)&ecv[j];
            int4 p1 = *(const int4*)&ecv[j + 2];
            int4 p2 = *(const int4*)&ecv[j + 4];
            int4 p3 = *(const int4*)&ecv[j + 6];
            uint2 d0 = *(const uint2*)(wb + ((uint_t)p0.x + l8));
            uint2 d1 = *(const uint2*)(wb + ((uint_t)p0.z + l8));
            uint2 d2 = *(const uint2*)(wb + ((uint_t)p1.x + l8));
            uint2 d3 = *(const uint2*)(wb + ((uint_t)p1.z + l8));
            uint2 d4 = *(const uint2*)(wb + ((uint_t)p2.x + l8));
            uint2 d5 = *(const uint2*)(wb + ((uint_t)p2.z + l8));
            uint2 d6 = *(const uint2*)(wb + ((uint_t)p3.x + l8));
            uint2 d7 = *(const uint2*)(wb + ((uint_t)p3.z + l8));
#define MAC4(D, VB) { \
            float v = __int_as_float(VB); \
            const _Float16* h = (const _Float16*)&D; \
            a0 = fmaf(v, (float)h[0], a0); \
            a1 = fmaf(v, (float)h[1], a1); \
            a2 = fmaf(v, (float)h[2], a2); \
            a3 = fmaf(v, (float)h[3], a3); }
            MAC4(d0, p0.y) MAC4(d1, p0.w)
            MAC4(d2, p1.y) MAC4(d3, p1.w)
            MAC4(d4, p2.y) MAC4(d5, p2.w)
            MAC4(d6, p3.y) MAC4(d7, p3.w)
#undef MAC4
        }
        union { _Float16 h[4]; uint2 u; } pk;
        pk.h[0] = (_Float16)fmaxf(a0, 0.0f);
        pk.h[1] = (_Float16)fmaxf(a1, 0.0f);
        pk.h[2] = (_Float16)fmaxf(a2, 0.0f);
        pk.h[3] = (_Float16)fmaxf(a3, 0.0f);
        if (c0 < 64) *(uint2*)&hb[(size_t)r * 192 + c0]        = pk.u;   // lanes 0-15
        else         *(uint2*)&xb[(size_t)r * 128 + (c0 - 64)] = pk.u;   // lanes 16-47
    }
}

// hop1: y = A @ xb. ONE WAVE PER ROW; lane owns cols 2l,2l+1; one dword (4B)
// gather per entry per wave (was 2). Slab e.x = col*128; xb byte stride 256
// -> byte off = (e.x<<1) + 4l. branch1 -> hb[:,64:128]; branch2 -> tmp[N,64].
__global__ void hop1_kernel(const int* __restrict__ fill, const int2* __restrict__ slab,
                            const _Float16* __restrict__ xb,
                            _Float16* __restrict__ hb, _Float16* __restrict__ tmp) {
    int lane = threadIdx.x & 63;
    int r = __builtin_amdgcn_readfirstlane((int)(blockIdx.x * 4 + (threadIdx.x >> 6)));
    const int2* ecv = slab + (size_t)r * SLAB_A;
    int e = (min(fill[(size_t)r * FILL_STRIDE], SLAB_A) + 7) & ~7;

    float a0 = 0.0f, a1 = 0.0f;
    uint_t l4 = 4u * (uint_t)lane;
    const char* xbb = (const char*)xb;

    for (int j = 0; j < e; j += 8) {
        int4 p0 = *(const int4*)&ecv[j];
        int4 p1 = *(const int4*)&ecv[j + 2];
        int4 p2 = *(const int4*)&ecv[j + 4];
        int4 p3 = *(const int4*)&ecv[j + 6];
        uint_t d0 = *(const uint_t*)(xbb + (((uint_t)p0.x << 1) + l4));
        uint_t d1 = *(const uint_t*)(xbb + (((uint_t)p0.z << 1) + l4));
        uint_t d2 = *(const uint_t*)(xbb + (((uint_t)p1.x << 1) + l4));
        uint_t d3 = *(const uint_t*)(xbb + (((uint_t)p1.z << 1) + l4));
        uint_t d4 = *(const uint_t*)(xbb + (((uint_t)p2.x << 1) + l4));
        uint_t d5 = *(const uint_t*)(xbb + (((uint_t)p2.z << 1) + l4));
        uint_t d6 = *(const uint_t*)(xbb + (((uint_t)p3.x << 1) + l4));
        uint_t d7 = *(const uint_t*)(xbb + (((uint_t)p3.z << 1) + l4));
#define MAC2(D, VB) { \
        float v = __int_as_float(VB); \
        const _Float16* h = (const _Float16*)&D; \
        a0 = fmaf(v, (float)h[0], a0); \
        a1 = fmaf(v, (float)h[1], a1); }
        MAC2(d0, p0.y) MAC2(d1, p0.w)
        MAC2(d2, p1.y) MAC2(d3, p1.w)
        MAC2(d4, p2.y) MAC2(d5, p2.w)
        MAC2(d6, p3.y) MAC2(d7, p3.w)
#undef MAC2
    }
    union { _Float16 h[2]; uint_t u; } pk;
    pk.h[0] = (_Float16)a0;
    pk.h[1] = (_Float16)a1;
    int c0 = 2 * lane;                        // 0..126
    if (c0 < 64) *(uint_t*)&hb[(size_t)r * 192 + 64 + c0]  = pk.u;   // lanes 0-31
    else         *(uint_t*)&tmp[(size_t)r * 64 + (c0 - 64)] = pk.u;  // lanes 32-63
}

// hop2: branch2 second hop -> hb[:,128:192]. ONE WAVE PER ROW; lane owns col
// lane; 2B gather (full 128B tmp row per wave-instr). Slab e.x = col*128 =
// tmp byte off.
__global__ void hop2_kernel(const int* __restrict__ fill, const int2* __restrict__ slab,
                            const _Float16* __restrict__ tmp, _Float16* __restrict__ hb) {
    int lane = threadIdx.x & 63;
    int r = __builtin_amdgcn_readfirstlane((int)(blockIdx.x * 4 + (threadIdx.x >> 6)));
    const int2* ecv = slab + (size_t)r * SLAB_A;
    int e = (min(fill[(size_t)r * FILL_STRIDE], SLAB_A) + 7) & ~7;

    float acc = 0.0f;
    uint_t l2 = 2u * (uint_t)lane;
    const char* tb = (const char*)tmp;

    for (int j = 0; j < e; j += 8) {
        int4 p0 = *(const int4*)&ecv[j];
        int4 p1 = *(const int4*)&ecv[j + 2];
        int4 p2 = *(const int4*)&ecv[j + 4];
        int4 p3 = *(const int4*)&ecv[j + 6];
        float f0 = (float)*(const _Float16*)(tb + ((uint_t)p0.x + l2));
        float f1 = (float)*(const _Float16*)(tb + ((uint_t)p0.z + l2));
        float f2 = (float)*(const _Float16*)(tb + ((uint_t)p1.x + l2));
        float f3 = (float)*(const _Float16*)(tb + ((uint_t)p1.z + l2));
        float f4 = (float)*(const _Float16*)(tb + ((uint_t)p2.x + l2));
        float f5 = (float)*(const _Float16*)(tb + ((uint_t)p2.z + l2));
        float f6 = (float)*(const _Float16*)(tb + ((uint_t)p3.x + l2));
        float f7 = (float)*(const _Float16*)(tb + ((uint_t)p3.z + l2));
        acc = fmaf(__int_as_float(p0.y), f0, acc);
        acc = fmaf(__int_as_float(p0.w), f1, acc);
        acc = fmaf(__int_as_float(p1.y), f2, acc);
        acc = fmaf(__int_as_float(p1.w), f3, acc);
        acc = fmaf(__int_as_float(p2.y), f4, acc);
        acc = fmaf(__int_as_float(p2.w), f5, acc);
        acc = fmaf(__int_as_float(p3.y), f6, acc);
        acc = fmaf(__int_as_float(p3.w), f7, acc);
    }
    hb[(size_t)r * 192 + 128 + lane] = (_Float16)acc;
}

// ---------------------------------------------------------------------------
// FC + log_softmax via MFMA (f16). Block = 3 waves; wave nt owns 16 cols;
// 16 rows per block; K=192 = 6 x mfma_f32_16x16x32_f16.
// D layout: col=lane&15, row=quad*4+reg (dtype-independent, verified).
// ---------------------------------------------------------------------------
__global__ void fc_mfma_kernel(const _Float16* __restrict__ hb,
                               const _Float16* __restrict__ fcwB,
                               const float* __restrict__ fc_b,
                               float* __restrict__ out) {
    int wave = threadIdx.x >> 6;      // 0..2 = N-tile
    int lane = threadIdx.x & 63;
    int m16  = lane & 15;
    int quad = lane >> 4;
    size_t rowbase = (size_t)blockIdx.x * 16;

    float4v acc = {0.f, 0.f, 0.f, 0.f};
    const _Float16* arow = hb   + (rowbase + m16) * 192 + quad * 8;
    const _Float16* brow = fcwB + (size_t)(wave * 16 + m16) * 192 + quad * 8;
#pragma unroll
    for (int s = 0; s < 6; ++s) {
        half8v a = *(const half8v*)(arow + s * 32);
        half8v b = *(const half8v*)(brow + s * 32);
        acc = __builtin_amdgcn_mfma_f32_16x16x32_f16(a, b, acc, 0, 0, 0);
    }

    __shared__ float lds[16][49];     // 48 cols + pad
    __shared__ float s_lse[16];
    int col = wave * 16 + m16;
    float bias = (col < NCLS) ? fc_b[col] : 0.0f;
#pragma unroll
    for (int i = 0; i < 4; ++i) {
        lds[quad * 4 + i][col] = acc[i] + bias;
    }
    __syncthreads();
    if (threadIdx.x < 16) {
        int row = threadIdx.x;
        float m = -INFINITY;
        for (int c = 0; c < NCLS; ++c) m = fmaxf(m, lds[row][c]);
        float s = 0.0f;
        for (int c = 0; c < NCLS; ++c) s += expf(lds[row][c] - m);
        s_lse[row] = m + logf(s);
    }
    __syncthreads();
    for (int idx = threadIdx.x; idx < 16 * NCLS; idx += 192) {
        int row = idx / NCLS, c = idx - row * NCLS;
        out[(rowbase + row) * NCLS + c] = lds[row][c] - s_lse[row];
    }
}

// ---------------------------------------------------------------------------

extern "C" void kernel_launch(void* const* d_in, const int* in_sizes, int n_in,
                              void* d_out, int out_size, void* d_ws, size_t ws_size,
                              hipStream_t stream) {
    const int*   adj_idx  = (const int*)  d_in[0];
    const float* adj_val  = (const float*)d_in[1];
    const int*   feat_idx = (const int*)  d_in[2];
    const float* feat_val = (const float*)d_in[3];
    const float* w1 = (const float*)d_in[4];
    const float* b1 = (const float*)d_in[5];
    const float* w2 = (const float*)d_in[6];
    const float* b2 = (const float*)d_in[7];
    const float* w3 = (const float*)d_in[8];
    const float* b3 = (const float*)d_in[9];
    const float* fc_w = (const float*)d_in[10];
    const float* fc_b = (const float*)d_in[11];
    float* out = (float*)d_out;

    char* ws = (char*)d_ws;
    size_t off = 0;
    auto take = [&](size_t bytes) -> char* {
        char* p = ws + off;
        off = (off + bytes + 255) & ~(size_t)255;
        return p;
    };
    int*       fills    = (int*)take((size_t)2 * N_NODES * FILL_STRIDE * sizeof(int)); // memset 0
    int*       featFill = fills;
    int*       adjFill  = fills + (size_t)N_NODES * FILL_STRIDE;
    int2*      featSlab = (int2*)take((size_t)N_NODES * SLAB_F * sizeof(int2));        // 32 MB
    int2*      adjSlab  = (int2*)take((size_t)N_NODES * SLAB_A * sizeof(int2));        // 19.2 MB
    _Float16*  tmp      = (_Float16*)featSlab;  // reuse: dead after spmm_feat (6.4MB fits)
    _Float16*  wcat     = (_Float16*)take((size_t)F_IN * 192 * sizeof(_Float16));      // 0.79 MB
    _Float16*  fcwB     = (_Float16*)take((size_t)48 * 192 * sizeof(_Float16));        // 18 KB
    _Float16*  xb       = (_Float16*)take((size_t)N_NODES * 128 * sizeof(_Float16));   // 12.8 MB
    _Float16*  hb       = (_Float16*)take((size_t)N_NODES * 192 * sizeof(_Float16));   // 19.2 MB

    hipMemsetAsync(fills, 0, (size_t)2 * N_NODES * FILL_STRIDE * sizeof(int), stream);

    wcat_kernel<<<(F_IN * HID + 255) / 256, 256, 0, stream>>>(w1, w2, w3, wcat);
    fcwb_kernel<<<(48 * 192 + 255) / 256, 256, 0, stream>>>(fc_w, fcwB);

    {
        const int step = (N_NODES + FEAT_PASSES - 1) / FEAT_PASSES;
        for (int p = 0; p < FEAT_PASSES; ++p) {
            slab_scatter_kernel<<<(NNZ_FEAT + 255) / 256, 256, 0, stream>>>(
                feat_idx, feat_idx + NNZ_FEAT, feat_val, NNZ_FEAT,
                p * step, min(N_NODES, (p + 1) * step), SLAB_F, 384, featFill, featSlab);
        }
    }
    {
        const int step = (N_NODES + ADJ_PASSES - 1) / ADJ_PASSES;
        for (int p = 0; p < ADJ_PASSES; ++p) {
            slab_scatter_kernel<<<(E_ADJ + 255) / 256, 256, 0, stream>>>(
                adj_idx, adj_idx + E_ADJ, adj_val, E_ADJ,
                p * step, min(N_NODES, (p + 1) * step), SLAB_A, 128, adjFill, adjSlab);
        }
    }

    // Zero-pad both slabs up to roundup8(own fill) so gather loops are branch-free.
    slab_pad_kernel<<<(2 * N_NODES * 8 + 255) / 256, 256, 0, stream>>>(
        featFill, featSlab, adjFill, adjSlab);

    spmm_feat_kernel<<<N_NODES / 4, 256, 0, stream>>>(featFill, featSlab, wcat,
                                                      b1, b2, b3, hb, xb);
    hop1_kernel<<<N_NODES / 4, 256, 0, stream>>>(adjFill, adjSlab, xb, hb, tmp);
    hop2_kernel<<<N_NODES / 4, 256, 0, stream>>>(adjFill, adjSlab, tmp, hb);
    fc_mfma_kernel<<<N_NODES / 16, 192, 0, stream>>>(hb, fcwB, fc_b, out);
}

// Round 3
// 345.072 us; speedup vs baseline: 1.0284x; 1.0284x over previous
//
#include <hip/hip_runtime.h>
#include <math.h>

#define N_NODES   50000
#define F_IN      2048
#define E_ADJ     800000
#define NNZ_FEAT  1600000
#define HID       64
#define NCLS      40
#define FEAT_PASSES 4
#define ADJ_PASSES  2

// Fixed-capacity per-row slabs (degrees Poisson(32)/Poisson(16), max ~58/~35).
#define SLAB_F    80    // 640 B / row (multiple of 8)
#define SLAB_A    48    // 384 B / row (multiple of 8)

// One fill counter per 64B cache line.
#define FILL_STRIDE 16

typedef unsigned short ushort_t;
typedef unsigned int   uint_t;
typedef _Float16 half8v __attribute__((ext_vector_type(8)));
typedef float    float4v __attribute__((ext_vector_type(4)));

// ---------------------------------------------------------------------------
// Slab scatter. e.x holds the PRE-SCALED byte offset (col*stride) so the SpMM
// gather address is a single 32-bit add; e.y holds the fp32 value bits.
// ---------------------------------------------------------------------------
__global__ void slab_scatter_kernel(const int* __restrict__ rows, const int* __restrict__ cols,
                                    const float* __restrict__ vals, int nnz,
                                    int rlo, int rhi, int slab_cap, int col_scale,
                                    int* __restrict__ fill, int2* __restrict__ slab) {
    int i = blockIdx.x * blockDim.x + threadIdx.x;
    if (i < nnz) {
        int r = rows[i];
        if (r >= rlo && r < rhi) {
            int p = atomicAdd(&fill[(size_t)r * FILL_STRIDE], 1);
            if (p < slab_cap) {
                int2 e;
                e.x = cols[i] * col_scale;
                e.y = __float_as_int(vals[i]);
                slab[(size_t)r * slab_cap + p] = e;
            }
        }
    }
}

// ---------------------------------------------------------------------------
// Zero-pad each slab row from its fill count up to roundup8(max over the row
// PAIR {r, r^1}). Padded entries are {byteoff 0, value 0.0f} -> fma no-ops.
// Gather kernels loop each pair to this bound with no tails; the pair
// predicate in-kernel computes the IDENTICAL bound.
// ---------------------------------------------------------------------------
__global__ void slab_pad_kernel(const int* __restrict__ featFill, int2* __restrict__ featSlab,
                                const int* __restrict__ adjFill,  int2* __restrict__ adjSlab) {
    int i = blockIdx.x * blockDim.x + threadIdx.x;
    const int perSlab = N_NODES * 8;
    const int* fill; int2* slab; int cap; int idx;
    if (i < perSlab)              { fill = featFill; slab = featSlab; cap = SLAB_F; idx = i; }
    else if (i < 2 * perSlab)     { fill = adjFill;  slab = adjSlab;  cap = SLAB_A; idx = i - perSlab; }
    else return;
    int r  = idx >> 3;
    int k  = idx & 7;
    int rm = r ^ 1;
    int s  = min(fill[(size_t)r  * FILL_STRIDE], cap);
    int sm = min(fill[(size_t)rm * FILL_STRIDE], cap);
    int tgt = (max(s, sm) + 7) & ~7;   // <= cap since cap % 8 == 0
    int2 z; z.x = 0; z.y = 0;
    for (int slot = s + k; slot < tgt; slot += 8)
        slab[(size_t)r * cap + slot] = z;
}

// Pack w1|w2|w3 -> fp16 wcat[2048][192].
__global__ void wcat_kernel(const float* __restrict__ w1, const float* __restrict__ w2,
                            const float* __restrict__ w3, _Float16* __restrict__ wcat) {
    int i = blockIdx.x * blockDim.x + threadIdx.x;     // over 2048*64
    if (i < F_IN * HID) {
        int f = i >> 6, c = i & 63;
        wcat[(size_t)f * 192 + c]       = (_Float16)w1[i];
        wcat[(size_t)f * 192 + 64 + c]  = (_Float16)w2[i];
        wcat[(size_t)f * 192 + 128 + c] = (_Float16)w3[i];
    }
}

// fc_w [192x40] -> class-major fp16 fcwB[48][192] (cols 40..47 zero).
__global__ void fcwb_kernel(const float* __restrict__ fc_w, _Float16* __restrict__ fcwB) {
    int i = blockIdx.x * blockDim.x + threadIdx.x;     // over 48*192
    if (i < 48 * 192) {
        int c = i / 192, k = i - c * 192;
        fcwB[i] = (c < NCLS) ? (_Float16)fc_w[k * NCLS + c] : (_Float16)0.0f;
    }
}

// ---------------------------------------------------------------------------
// SpMM feat @ wcat + bias, relu. 4 ROWS PER BLOCK (two pairs), 192 threads;
// thread t owns col t for all 4 rows. Slab staged to LDS once (loop has NO
// slab VMEM); 32 independent 2B gathers per iter per thread-stream set.
// __launch_bounds__(192,1) opens the VGPR budget so gathers stay in flight.
// Branch0 -> hb[:,0:64]; br 1,2 -> xb[N,128].
// ---------------------------------------------------------------------------
__global__ __launch_bounds__(192, 1)
void spmm_feat_kernel(const int* __restrict__ fill, const int2* __restrict__ slab,
                      const _Float16* __restrict__ wcat,
                      const float* __restrict__ b1, const float* __restrict__ b2,
                      const float* __restrict__ b3,
                      _Float16* __restrict__ hb, _Float16* __restrict__ xb) {
    __shared__ int2 sl[4][SLAB_F];
    int t = threadIdx.x;                 // 0..191
    int base = blockIdx.x * 4;

    // Stage 4 contiguous slab rows (2560 B) -> LDS. 160 int4s.
    const int4* src = (const int4*)(slab + (size_t)base * SLAB_F);
    if (t < 160) ((int4*)&sl[0][0])[t] = src[t];

    int e0 = min(fill[(size_t)(base + 0) * FILL_STRIDE], SLAB_F);
    int e1 = min(fill[(size_t)(base + 1) * FILL_STRIDE], SLAB_F);
    int e2 = min(fill[(size_t)(base + 2) * FILL_STRIDE], SLAB_F);
    int e3 = min(fill[(size_t)(base + 3) * FILL_STRIDE], SLAB_F);
    int e01 = (max(e0, e1) + 7) & ~7;    // matches slab_pad target
    int e23 = (max(e2, e3) + 7) & ~7;
    int emax = max(e01, e23);
    __syncthreads();

    int br = t >> 6, c = t & 63;
    const float* bsel = (br == 0) ? b1 : (br == 1) ? b2 : b3;
    float bias = bsel[c];
    float a0 = bias, a1 = bias, a2 = bias, a3 = bias;
    uint_t t2 = 2u * (uint_t)t;
    const char* wb = (const char*)wcat;

    for (int j = 0; j < emax; j += 8) {
        if (j < e01) {
            int2 Ea[8], Eb[8];
#pragma unroll
            for (int k = 0; k < 8; ++k) { Ea[k] = sl[0][j + k]; Eb[k] = sl[1][j + k]; }
            float ga[8], gb[8];
#pragma unroll
            for (int k = 0; k < 8; ++k) ga[k] = (float)*(const _Float16*)(wb + ((uint_t)Ea[k].x + t2));
#pragma unroll
            for (int k = 0; k < 8; ++k) gb[k] = (float)*(const _Float16*)(wb + ((uint_t)Eb[k].x + t2));
#pragma unroll
            for (int k = 0; k < 8; ++k) a0 = fmaf(__int_as_float(Ea[k].y), ga[k], a0);
#pragma unroll
            for (int k = 0; k < 8; ++k) a1 = fmaf(__int_as_float(Eb[k].y), gb[k], a1);
        }
        if (j < e23) {
            int2 Ea[8], Eb[8];
#pragma unroll
            for (int k = 0; k < 8; ++k) { Ea[k] = sl[2][j + k]; Eb[k] = sl[3][j + k]; }
            float ga[8], gb[8];
#pragma unroll
            for (int k = 0; k < 8; ++k) ga[k] = (float)*(const _Float16*)(wb + ((uint_t)Ea[k].x + t2));
#pragma unroll
            for (int k = 0; k < 8; ++k) gb[k] = (float)*(const _Float16*)(wb + ((uint_t)Eb[k].x + t2));
#pragma unroll
            for (int k = 0; k < 8; ++k) a2 = fmaf(__int_as_float(Ea[k].y), ga[k], a2);
#pragma unroll
            for (int k = 0; k < 8; ++k) a3 = fmaf(__int_as_float(Eb[k].y), gb[k], a3);
        }
    }

    float r0 = fmaxf(a0, 0.0f), r1 = fmaxf(a1, 0.0f);
    float r2 = fmaxf(a2, 0.0f), r3 = fmaxf(a3, 0.0f);
    if (br == 0) {
        hb[(size_t)(base + 0) * 192 + c] = (_Float16)r0;
        hb[(size_t)(base + 1) * 192 + c] = (_Float16)r1;
        hb[(size_t)(base + 2) * 192 + c] = (_Float16)r2;
        hb[(size_t)(base + 3) * 192 + c] = (_Float16)r3;
    } else {
        size_t cc = (size_t)(br - 1) * 64 + c;
        xb[(size_t)(base + 0) * 128 + cc] = (_Float16)r0;
        xb[(size_t)(base + 1) * 128 + cc] = (_Float16)r1;
        xb[(size_t)(base + 2) * 128 + cc] = (_Float16)r2;
        xb[(size_t)(base + 3) * 128 + cc] = (_Float16)r3;
    }
}

// hop1: y = A @ xb. 4 rows/block, 128 threads; thread t owns col t. LDS slab.
// Slab e.x = col*128; xb byte stride 256 -> off = (e.x<<1) + 2t.
// branch1 -> hb[:,64:128]; branch2 -> tmp[N,64].
__global__ __launch_bounds__(128, 1)
void hop1_kernel(const int* __restrict__ fill, const int2* __restrict__ slab,
                 const _Float16* __restrict__ xb,
                 _Float16* __restrict__ hb, _Float16* __restrict__ tmp) {
    __shared__ int2 sl[4][SLAB_A];
    int t = threadIdx.x;                 // 0..127
    int base = blockIdx.x * 4;

    const int4* src = (const int4*)(slab + (size_t)base * SLAB_A);
    if (t < 96) ((int4*)&sl[0][0])[t] = src[t];

    int e0 = min(fill[(size_t)(base + 0) * FILL_STRIDE], SLAB_A);
    int e1 = min(fill[(size_t)(base + 1) * FILL_STRIDE], SLAB_A);
    int e2 = min(fill[(size_t)(base + 2) * FILL_STRIDE], SLAB_A);
    int e3 = min(fill[(size_t)(base + 3) * FILL_STRIDE], SLAB_A);
    int e01 = (max(e0, e1) + 7) & ~7;
    int e23 = (max(e2, e3) + 7) & ~7;
    int emax = max(e01, e23);
    __syncthreads();

    float a0 = 0.0f, a1 = 0.0f, a2 = 0.0f, a3 = 0.0f;
    uint_t t2 = 2u * (uint_t)t;
    const char* xbb = (const char*)xb;

    for (int j = 0; j < emax; j += 8) {
        if (j < e01) {
            int2 Ea[8], Eb[8];
#pragma unroll
            for (int k = 0; k < 8; ++k) { Ea[k] = sl[0][j + k]; Eb[k] = sl[1][j + k]; }
            float ga[8], gb[8];
#pragma unroll
            for (int k = 0; k < 8; ++k) ga[k] = (float)*(const _Float16*)(xbb + (((uint_t)Ea[k].x << 1) + t2));
#pragma unroll
            for (int k = 0; k < 8; ++k) gb[k] = (float)*(const _Float16*)(xbb + (((uint_t)Eb[k].x << 1) + t2));
#pragma unroll
            for (int k = 0; k < 8; ++k) a0 = fmaf(__int_as_float(Ea[k].y), ga[k], a0);
#pragma unroll
            for (int k = 0; k < 8; ++k) a1 = fmaf(__int_as_float(Eb[k].y), gb[k], a1);
        }
        if (j < e23) {
            int2 Ea[8], Eb[8];
#pragma unroll
            for (int k = 0; k < 8; ++k) { Ea[k] = sl[2][j + k]; Eb[k] = sl[3][j + k]; }
            float ga[8], gb[8];
#pragma unroll
            for (int k = 0; k < 8; ++k) ga[k] = (float)*(const _Float16*)(xbb + (((uint_t)Ea[k].x << 1) + t2));
#pragma unroll
            for (int k = 0; k < 8; ++k) gb[k] = (float)*(const _Float16*)(xbb + (((uint_t)Eb[k].x << 1) + t2));
#pragma unroll
            for (int k = 0; k < 8; ++k) a2 = fmaf(__int_as_float(Ea[k].y), ga[k], a2);
#pragma unroll
            for (int k = 0; k < 8; ++k) a3 = fmaf(__int_as_float(Eb[k].y), gb[k], a3);
        }
    }

    if (t < 64) {
        hb[(size_t)(base + 0) * 192 + 64 + t] = (_Float16)a0;
        hb[(size_t)(base + 1) * 192 + 64 + t] = (_Float16)a1;
        hb[(size_t)(base + 2) * 192 + 64 + t] = (_Float16)a2;
        hb[(size_t)(base + 3) * 192 + 64 + t] = (_Float16)a3;
    } else {
        int c = t - 64;
        tmp[(size_t)(base + 0) * 64 + c] = (_Float16)a0;
        tmp[(size_t)(base + 1) * 64 + c] = (_Float16)a1;
        tmp[(size_t)(base + 2) * 64 + c] = (_Float16)a2;
        tmp[(size_t)(base + 3) * 64 + c] = (_Float16)a3;
    }
}

// hop2: branch2 second hop -> hb[:,128:192]. 4 rows/block, 64 threads (1 wave);
// thread t owns col t. Slab e.x = col*128 = tmp byte off.
__global__ __launch_bounds__(64, 1)
void hop2_kernel(const int* __restrict__ fill, const int2* __restrict__ slab,
                 const _Float16* __restrict__ tmp, _Float16* __restrict__ hb) {
    __shared__ int2 sl[4][SLAB_A];
    int t = threadIdx.x;                 // 0..63
    int base = blockIdx.x * 4;

    const int4* src = (const int4*)(slab + (size_t)base * SLAB_A);
    int4* dst = (int4*)&sl[0][0];
    for (int i = t; i < 96; i += 64) dst[i] = src[i];

    int e0 = min(fill[(size_t)(base + 0) * FILL_STRIDE], SLAB_A);
    int e1 = min(fill[(size_t)(base + 1) * FILL_STRIDE], SLAB_A);
    int e2 = min(fill[(size_t)(base + 2) * FILL_STRIDE], SLAB_A);
    int e3 = min(fill[(size_t)(base + 3) * FILL_STRIDE], SLAB_A);
    int e01 = (max(e0, e1) + 7) & ~7;
    int e23 = (max(e2, e3) + 7) & ~7;
    int emax = max(e01, e23);
    __syncthreads();

    float a0 = 0.0f, a1 = 0.0f, a2 = 0.0f, a3 = 0.0f;
    uint_t t2 = 2u * (uint_t)t;
    const char* tb = (const char*)tmp;

    for (int j = 0; j < emax; j += 8) {
        if (j < e01) {
            int2 Ea[8], Eb[8];
#pragma unroll
            for (int k = 0; k < 8; ++k) { Ea[k] = sl[0][j + k]; Eb[k] = sl[1][j + k]; }
            float ga[8], gb[8];
#pragma unroll
            for (int k = 0; k < 8; ++k) ga[k] = (float)*(const _Float16*)(tb + ((uint_t)Ea[k].x + t2));
#pragma unroll
            for (int k = 0; k < 8; ++k) gb[k] = (float)*(const _Float16*)(tb + ((uint_t)Eb[k].x + t2));
#pragma unroll
            for (int k = 0; k < 8; ++k) a0 = fmaf(__int_as_float(Ea[k].y), ga[k], a0);
#pragma unroll
            for (int k = 0; k < 8; ++k) a1 = fmaf(__int_as_float(Eb[k].y), gb[k], a1);
        }
        if (j < e23) {
            int2 Ea[8], Eb[8];
#pragma unroll
            for (int k = 0; k < 8; ++k) { Ea[k] = sl[2][j + k]; Eb[k] = sl[3][j + k]; }
            float ga[8], gb[8];
#pragma unroll
            for (int k = 0; k < 8; ++k) ga[k] = (float)*(const _Float16*)(tb + ((uint_t)Ea[k].x + t2));
#pragma unroll
            for (int k = 0; k < 8; ++k) gb[k] = (float)*(const _Float16*)(tb + ((uint_t)Eb[k].x + t2));
#pragma unroll
            for (int k = 0; k < 8; ++k) a2 = fmaf(__int_as_float(Ea[k].y), ga[k], a2);
#pragma unroll
            for (int k = 0; k < 8; ++k) a3 = fmaf(__int_as_float(Eb[k].y), gb[k], a3);
        }
    }

    hb[(size_t)(base + 0) * 192 + 128 + t] = (_Float16)a0;
    hb[(size_t)(base + 1) * 192 + 128 + t] = (_Float16)a1;
    hb[(size_t)(base + 2) * 192 + 128 + t] = (_Float16)a2;
    hb[(size_t)(base + 3) * 192 + 128 + t] = (_Float16)a3;
}

// ---------------------------------------------------------------------------
// FC + log_softmax via MFMA (f16). Block = 3 waves; wave nt owns 16 cols;
// 16 rows per block; K=192 = 6 x mfma_f32_16x16x32_f16.
// D layout: col=lane&15, row=quad*4+reg (dtype-independent, verified).
// ---------------------------------------------------------------------------
__global__ void fc_mfma_kernel(const _Float16* __restrict__ hb,
                               const _Float16* __restrict__ fcwB,
                               const float* __restrict__ fc_b,
                               float* __restrict__ out) {
    int wave = threadIdx.x >> 6;      // 0..2 = N-tile
    int lane = threadIdx.x & 63;
    int m16  = lane & 15;
    int quad = lane >> 4;
    size_t rowbase = (size_t)blockIdx.x * 16;

    float4v acc = {0.f, 0.f, 0.f, 0.f};
    const _Float16* arow = hb   + (rowbase + m16) * 192 + quad * 8;
    const _Float16* brow = fcwB + (size_t)(wave * 16 + m16) * 192 + quad * 8;
#pragma unroll
    for (int s = 0; s < 6; ++s) {
        half8v a = *(const half8v*)(arow + s * 32);
        half8v b = *(const half8v*)(brow + s * 32);
        acc = __builtin_amdgcn_mfma_f32_16x16x32_f16(a, b, acc, 0, 0, 0);
    }

    __shared__ float lds[16][49];     // 48 cols + pad
    __shared__ float s_lse[16];
    int col = wave * 16 + m16;
    float bias = (col < NCLS) ? fc_b[col] : 0.0f;
#pragma unroll
    for (int i = 0; i < 4; ++i) {
        lds[quad * 4 + i][col] = acc[i] + bias;
    }
    __syncthreads();
    if (threadIdx.x < 16) {
        int row = threadIdx.x;
        float m = -INFINITY;
        for (int c = 0; c < NCLS; ++c) m = fmaxf(m, lds[row][c]);
        float s = 0.0f;
        for (int c = 0; c < NCLS; ++c) s += expf(lds[row][c] - m);
        s_lse[row] = m + logf(s);
    }
    __syncthreads();
    for (int idx = threadIdx.x; idx < 16 * NCLS; idx += 192) {
        int row = idx / NCLS, c = idx - row * NCLS;
        out[(rowbase + row) * NCLS + c] = lds[row][c] - s_lse[row];
    }
}

// ---------------------------------------------------------------------------

extern "C" void kernel_launch(void* const* d_in, const int* in_sizes, int n_in,
                              void* d_out, int out_size, void* d_ws, size_t ws_size,
                              hipStream_t stream) {
    const int*   adj_idx  = (const int*)  d_in[0];
    const float* adj_val  = (const float*)d_in[1];
    const int*   feat_idx = (const int*)  d_in[2];
    const float* feat_val = (const float*)d_in[3];
    const float* w1 = (const float*)d_in[4];
    const float* b1 = (const float*)d_in[5];
    const float* w2 = (const float*)d_in[6];
    const float* b2 = (const float*)d_in[7];
    const float* w3 = (const float*)d_in[8];
    const float* b3 = (const float*)d_in[9];
    const float* fc_w = (const float*)d_in[10];
    const float* fc_b = (const float*)d_in[11];
    float* out = (float*)d_out;

    char* ws = (char*)d_ws;
    size_t off = 0;
    auto take = [&](size_t bytes) -> char* {
        char* p = ws + off;
        off = (off + bytes + 255) & ~(size_t)255;
        return p;
    };
    int*       fills    = (int*)take((size_t)2 * N_NODES * FILL_STRIDE * sizeof(int)); // memset 0
    int*       featFill = fills;
    int*       adjFill  = fills + (size_t)N_NODES * FILL_STRIDE;
    int2*      featSlab = (int2*)take((size_t)N_NODES * SLAB_F * sizeof(int2));        // 32 MB
    int2*      adjSlab  = (int2*)take((size_t)N_NODES * SLAB_A * sizeof(int2));        // 19.2 MB
    _Float16*  tmp      = (_Float16*)featSlab;  // reuse: dead after spmm_feat (6.4MB fits)
    _Float16*  wcat     = (_Float16*)take((size_t)F_IN * 192 * sizeof(_Float16));      // 0.79 MB
    _Float16*  fcwB     = (_Float16*)take((size_t)48 * 192 * sizeof(_Float16));        // 18 KB
    _Float16*  xb       = (_Float16*)take((size_t)N_NODES * 128 * sizeof(_Float16));   // 12.8 MB
    _Float16*  hb       = (_Float16*)take((size_t)N_NODES * 192 * sizeof(_Float16));   // 19.2 MB

    hipMemsetAsync(fills, 0, (size_t)2 * N_NODES * FILL_STRIDE * sizeof(int), stream);

    wcat_kernel<<<(F_IN * HID + 255) / 256, 256, 0, stream>>>(w1, w2, w3, wcat);
    fcwb_kernel<<<(48 * 192 + 255) / 256, 256, 0, stream>>>(fc_w, fcwB);

    {
        const int step = (N_NODES + FEAT_PASSES - 1) / FEAT_PASSES;
        for (int p = 0; p < FEAT_PASSES; ++p) {
            slab_scatter_kernel<<<(NNZ_FEAT + 255) / 256, 256, 0, stream>>>(
                feat_idx, feat_idx + NNZ_FEAT, feat_val, NNZ_FEAT,
                p * step, min(N_NODES, (p + 1) * step), SLAB_F, 384, featFill, featSlab);
        }
    }
    {
        const int step = (N_NODES + ADJ_PASSES - 1) / ADJ_PASSES;
        for (int p = 0; p < ADJ_PASSES; ++p) {
            slab_scatter_kernel<<<(E_ADJ + 255) / 256, 256, 0, stream>>>(
                adj_idx, adj_idx + E_ADJ, adj_val, E_ADJ,
                p * step, min(N_NODES, (p + 1) * step), SLAB_A, 128, adjFill, adjSlab);
        }
    }

    // Zero-pad both slabs up to roundup8(pair max) so gather loops are branch-free.
    slab_pad_kernel<<<(2 * N_NODES * 8 + 255) / 256, 256, 0, stream>>>(
        featFill, featSlab, adjFill, adjSlab);

    spmm_feat_kernel<<<N_NODES / 4, 192, 0, stream>>>(featFill, featSlab, wcat,
                                                      b1, b2, b3, hb, xb);
    hop1_kernel<<<N_NODES / 4, 128, 0, stream>>>(adjFill, adjSlab, xb, hb, tmp);
    hop2_kernel<<<N_NODES / 4, 64, 0, stream>>>(adjFill, adjSlab, tmp, hb);
    fc_mfma_kernel<<<N_NODES / 16, 192, 0, stream>>>(hb, fcwB, fc_b, out);
}